// Round 4
// baseline (816.833 us; speedup 1.0000x reference)
//
#include <hip/hip_runtime.h>

#define L_FULL 65536
#define BATCH 256
#define F_TAPS 32

// ---------------- Kernel A: level-1 decomposition ----------------
// a1[j] = sum_k ho[k] * x[(2j+k-15) mod L] ; d1[j] with g[k] = (-1)^(k+1) ho[31-k].
// d1 -> energy[b*L + j] ; a1 -> apr[b*L + j] (appr region used as scratch)
constexpr int A_THREADS = 256;
constexpr int A_OUT = 2048;
constexpr int A_BLOCKS_PER_B = (L_FULL / 2) / A_OUT;  // 16

__global__ __launch_bounds__(A_THREADS) void level1_kernel(
    const float* __restrict__ x, const float* __restrict__ ho,
    float* __restrict__ energy, float* __restrict__ apr)
{
    __shared__ float xs[2 * A_OUT + 32];
    const int tid = threadIdx.x;
    const int b = blockIdx.x / A_BLOCKS_PER_B;
    const int chunk = blockIdx.x % A_BLOCKS_PER_B;
    const int j0 = chunk * A_OUT;

    const float* xb = x + (size_t)b * L_FULL;
    const int base = 2 * j0 - 15;
    for (int t = tid; t < 2 * A_OUT + 31; t += A_THREADS)
        xs[t] = xb[(base + t) & (L_FULL - 1)];
    __syncthreads();

    float* eb = energy + (size_t)b * L_FULL;
    float* ab = apr + (size_t)b * L_FULL;
    #pragma unroll
    for (int it = 0; it < A_OUT / A_THREADS; ++it) {
        const int j = tid + it * A_THREADS;
        const float* p = &xs[2 * j];           // xs[t] = x[base+t], window x[2j-15..2j+16]
        float aa = 0.f, dd = 0.f;
        #pragma unroll
        for (int k = 0; k < F_TAPS; ++k) {
            const float v = p[k];
            aa += ho[k] * v;                                   // SGPR filter
            dd += (k & 1) ? ho[31 - k] * v : -ho[31 - k] * v;  // sign folds into FMA
        }
        eb[j0 + j] = dd;
        ab[j0 + j] = aa;
    }
}

// ---------------- Kernel B: levels 2..8 + full reconstruction ----------------
constexpr int B_THREADS = 1024;
constexpr int SB_HALO = 16;
constexpr int SBUF_N = L_FULL / 2 + 2 * SB_HALO;   // 32800 floats
constexpr int DBUF_N = 4096 + 16;                  // staged dseg (halo 8 each side)

// one decomposition level in LDS. sbuf[SB_HALO + i] = a[i], i in [-16, N+16).
// a(new) -> sbuf (with halos), details -> dglob[0..N/2).
template<int N>
__device__ inline void decomp_step(float* sbuf, const float* __restrict__ ho,
                                   float* __restrict__ dglob, int tid)
{
    constexpr int M = N / 2;
    constexpr int PT = (M + B_THREADS - 1) / B_THREADS;
    float acc[PT];
    #pragma unroll
    for (int it = 0; it < PT; ++it) {
        const int j = tid + it * B_THREADS;
        float aa = 0.f;
        if (j < M) {
            const float* p = &sbuf[2 * j + 1];   // = a[2j-15 .. 2j+16], mod-free
            float dd = 0.f;
            #pragma unroll
            for (int k = 0; k < F_TAPS; ++k) {
                const float v = p[k];
                aa += ho[k] * v;
                dd += (k & 1) ? ho[31 - k] * v : -ho[31 - k] * v;
            }
            dglob[j] = dd;
        }
        acc[it] = aa;
    }
    __syncthreads();
    #pragma unroll
    for (int it = 0; it < PT; ++it) {
        const int j = tid + it * B_THREADS;
        if (j < M) {
            sbuf[SB_HALO + j] = acc[it];
            if (j < SB_HALO)      sbuf[SB_HALO + M + j] = acc[it];  // right halo
            if (j >= M - SB_HALO) sbuf[j - M + SB_HALO] = acc[it];  // left halo
        }
    }
    __syncthreads();
}

// one reconstruction iteration: appr (len S, sbuf w/ halo) + dseg (len S) -> len 2S.
// Outputs j=2m and j=(2m-1) mod 2S share window w = m-8+t (t in [0,16)):
//   out[2m]   += ho[31-2t]*a[w] + ho[2t]*d[w]
//   out[2m-1] += ho[30-2t]*a[w] - ho[2t+1]*d[w]
template<int S, bool STAGE_D>
__device__ inline void recon_step(float* sbuf, float* dbuf,
                                  const float* __restrict__ dglob,
                                  const float* __restrict__ ho, int tid)
{
    constexpr int N2 = 2 * S;
    constexpr int PT = (S + B_THREADS - 1) / B_THREADS;
    if (STAGE_D) {
        for (int t = tid; t < S + 16; t += B_THREADS)
            dbuf[t] = dglob[(t - 8) & (S - 1)];
        __syncthreads();
    }
    float acc_e[PT], acc_o[PT];
    #pragma unroll
    for (int it = 0; it < PT; ++it) {
        const int m = tid + it * B_THREADS;
        float oe = 0.f, oo = 0.f;
        if (m < S) {
            const float* pa = &sbuf[SB_HALO + m - 8];
            float dwin[16];
            if (STAGE_D) {
                const float* pd = &dbuf[m];
                #pragma unroll
                for (int t = 0; t < 16; ++t) dwin[t] = pd[t];
            } else if (m >= 8 && m < S - 7) {
                #pragma unroll
                for (int t = 0; t < 16; ++t) dwin[t] = dglob[m - 8 + t];
            } else {
                #pragma unroll
                for (int t = 0; t < 16; ++t) dwin[t] = dglob[(m - 8 + t) & (S - 1)];
            }
            #pragma unroll
            for (int t = 0; t < 16; ++t) {
                const float av = pa[t];
                const float dv = dwin[t];
                oe += ho[31 - 2 * t] * av + ho[2 * t] * dv;
                oo += ho[30 - 2 * t] * av - ho[2 * t + 1] * dv;
            }
        }
        acc_e[it] = oe; acc_o[it] = oo;
    }
    __syncthreads();
    #pragma unroll
    for (int it = 0; it < PT; ++it) {
        const int m = tid + it * B_THREADS;
        if (m < S) {
            const int je = 2 * m;
            const int jo = (2 * m - 1) & (N2 - 1);
            sbuf[SB_HALO + je] = acc_e[it];
            if (je < SB_HALO)       sbuf[SB_HALO + N2 + je] = acc_e[it];
            if (je >= N2 - SB_HALO) sbuf[je - N2 + SB_HALO] = acc_e[it];
            sbuf[SB_HALO + jo] = acc_o[it];
            if (jo < SB_HALO)       sbuf[SB_HALO + N2 + jo] = acc_o[it];
            if (jo >= N2 - SB_HALO) sbuf[jo - N2 + SB_HALO] = acc_o[it];
        }
    }
    __syncthreads();
}

__global__ __launch_bounds__(B_THREADS) void wavelet_kernel(
    const float* __restrict__ ho, float* __restrict__ energy, float* __restrict__ apr)
{
    __shared__ float sbuf[SBUF_N];     // 131,200 B
    __shared__ float dbuf[DBUF_N];     //  16,448 B  (total 147,648 <= 160 KiB)
    const int tid = threadIdx.x;
    const int b = blockIdx.x;
    float* eb = energy + (size_t)b * L_FULL;
    float* ab = apr + (size_t)b * L_FULL;

    // load a1 (from kernel A) with circular halo
    for (int t = tid; t < SBUF_N; t += B_THREADS)
        sbuf[t] = ab[(t - SB_HALO) & (L_FULL / 2 - 1)];
    __syncthreads();

    // ---- decomposition, levels 2..8 (detail l at energy offset 65536 - (65536>>(l-1))) ----
    decomp_step<32768>(sbuf, ho, eb + 32768, tid);
    decomp_step<16384>(sbuf, ho, eb + 49152, tid);
    decomp_step< 8192>(sbuf, ho, eb + 57344, tid);
    decomp_step< 4096>(sbuf, ho, eb + 61440, tid);
    decomp_step< 2048>(sbuf, ho, eb + 63488, tid);
    decomp_step< 1024>(sbuf, ho, eb + 64512, tid);
    decomp_step<  512>(sbuf, ho, eb + 65024, tid);

    // a8 -> energy tail [65280, 65536)
    if (tid < 256) eb[65280 + tid] = sbuf[SB_HALO + tid];
    __syncthreads();

    // ---- reconstruction ----
    recon_step<  256, true >(sbuf, dbuf, eb + 65024, ho, tid);  // d8 -> 512
    recon_step<  512, true >(sbuf, dbuf, eb + 64512, ho, tid);  // d7 -> 1024
    recon_step< 1024, true >(sbuf, dbuf, eb + 63488, ho, tid);  // d6 -> 2048
    recon_step< 2048, true >(sbuf, dbuf, eb + 61440, ho, tid);  // d5 -> 4096
    recon_step< 4096, true >(sbuf, dbuf, eb + 57344, ho, tid);  // d4 -> 8192
    recon_step< 8192, false>(sbuf, dbuf, eb + 49152, ho, tid);  // d3 -> 16384
    recon_step<16384, false>(sbuf, dbuf, eb + 32768, ho, tid);  // d2 -> 32768

    // final iteration: 32768 -> 65536, d1 = eb[0..32768), write appr directly
    {
        constexpr int S = L_FULL / 2;
        const float* d1 = eb;
        #pragma unroll 4
        for (int it = 0; it < S / B_THREADS; ++it) {   // 32 iterations
            const int m = tid + it * B_THREADS;
            const float* pa = &sbuf[SB_HALO + m - 8];
            float dwin[16];
            if (m >= 8 && m < S - 7) {
                #pragma unroll
                for (int t = 0; t < 16; ++t) dwin[t] = d1[m - 8 + t];
            } else {
                #pragma unroll
                for (int t = 0; t < 16; ++t) dwin[t] = d1[(m - 8 + t) & (S - 1)];
            }
            float oe = 0.f, oo = 0.f;
            #pragma unroll
            for (int t = 0; t < 16; ++t) {
                const float av = pa[t];
                const float dv = dwin[t];
                oe += ho[31 - 2 * t] * av + ho[2 * t] * dv;
                oo += ho[30 - 2 * t] * av - ho[2 * t + 1] * dv;
            }
            ab[2 * m] = oe;
            ab[(2 * m - 1) & (L_FULL - 1)] = oo;
        }
    }
}

extern "C" void kernel_launch(void* const* d_in, const int* in_sizes, int n_in,
                              void* d_out, int out_size, void* d_ws, size_t ws_size,
                              hipStream_t stream)
{
    const float* x  = (const float*)d_in[0];
    const float* ho = (const float*)d_in[1];
    float* energy = (float*)d_out;                       // output 0: 256*65536
    float* apr    = energy + (size_t)BATCH * L_FULL;     // output 1: 256*65536

    level1_kernel<<<BATCH * A_BLOCKS_PER_B, A_THREADS, 0, stream>>>(x, ho, energy, apr);
    wavelet_kernel<<<BATCH, B_THREADS, 0, stream>>>(ho, energy, apr);
}

// Round 7
// 801.719 us; speedup vs baseline: 1.0189x; 1.0189x over previous
//
#include <hip/hip_runtime.h>

#define L_FULL 65536
#define BATCH 256
#define F_TAPS 32

// ---------------- Kernel A: level-1 decomposition ----------------
// a1[j] = sum_k ho[k] * x[(2j+k-15) mod L] ; d1[j] with g[k] = (-1)^(k+1) ho[31-k].
// d1 -> energy[b*L + j] ; a1 -> apr[b*L + j] (appr region used as scratch)
constexpr int A_THREADS = 256;
constexpr int A_OUT = 2048;
constexpr int A_BLOCKS_PER_B = (L_FULL / 2) / A_OUT;  // 16

__global__ __launch_bounds__(A_THREADS, 4) void level1_kernel(
    const float* __restrict__ x, const float* __restrict__ ho,
    float* __restrict__ energy, float* __restrict__ apr)
{
    __shared__ float xs[2 * A_OUT + 32];
    const int tid = threadIdx.x;
    const int b = blockIdx.x / A_BLOCKS_PER_B;
    const int chunk = blockIdx.x % A_BLOCKS_PER_B;
    const int j0 = chunk * A_OUT;

    const float* xb = x + (size_t)b * L_FULL;
    // xs[t] = x[(2*j0 - 16 + t) mod L]; base is 16B-aligned so float4 loads
    // never straddle the circular boundary (L is a multiple of 4).
    constexpr int NF4 = (2 * A_OUT + 32) / 4;   // 1032
    for (int q = tid; q < NF4; q += A_THREADS) {
        const int fidx = (2 * j0 - 16 + 4 * q) & (L_FULL - 1);
        *reinterpret_cast<float4*>(&xs[4 * q]) =
            *reinterpret_cast<const float4*>(&xb[fidx]);
    }
    __syncthreads();

    float* eb = energy + (size_t)b * L_FULL;
    float* ab = apr + (size_t)b * L_FULL;
    #pragma unroll
    for (int it = 0; it < A_OUT / A_THREADS; ++it) {
        const int j = tid + it * A_THREADS;     // local output index
        const float* p = &xs[2 * j + 1];        // window x[2(j0+j)-15 .. +16]
        float aa = 0.f, dd = 0.f;
        #pragma unroll
        for (int k = 0; k < F_TAPS; ++k) {
            const float v = p[k];
            aa += ho[k] * v;                                   // SGPR filter
            dd += (k & 1) ? ho[31 - k] * v : -ho[31 - k] * v;  // sign folds into FMA
        }
        eb[j0 + j] = dd;
        ab[j0 + j] = aa;
    }
}

// ---------------- Kernel B: levels 2..8 + full reconstruction ----------------
constexpr int B_THREADS = 1024;
constexpr int SB_HALO = 16;
constexpr int SBUF_N = L_FULL / 2 + 2 * SB_HALO;   // 32800 floats
constexpr int DBUF_N = 4096 + 16;                  // staged dseg (halo 8 each side)

// one decomposition level in LDS. sbuf[SB_HALO + i] = a[i], i in [-16, N+16).
// a(new) -> sbuf (with halos), details -> dglob[0..N/2).
template<int N>
__device__ inline void decomp_step(float* sbuf, const float* __restrict__ ho,
                                   float* __restrict__ dglob, int tid)
{
    constexpr int M = N / 2;
    constexpr int PT = (M + B_THREADS - 1) / B_THREADS;
    float acc[PT];
    #pragma unroll
    for (int it = 0; it < PT; ++it) {
        const int j = tid + it * B_THREADS;
        float aa = 0.f;
        if (j < M) {
            const float* p = &sbuf[2 * j + 1];   // = a[2j-15 .. 2j+16], mod-free
            float dd = 0.f;
            #pragma unroll
            for (int k = 0; k < F_TAPS; ++k) {
                const float v = p[k];
                aa += ho[k] * v;
                dd += (k & 1) ? ho[31 - k] * v : -ho[31 - k] * v;
            }
            dglob[j] = dd;
        }
        acc[it] = aa;
    }
    __syncthreads();
    #pragma unroll
    for (int it = 0; it < PT; ++it) {
        const int j = tid + it * B_THREADS;
        if (j < M) {
            sbuf[SB_HALO + j] = acc[it];
            if (j < SB_HALO)      sbuf[SB_HALO + M + j] = acc[it];  // right halo
            if (j >= M - SB_HALO) sbuf[j - M + SB_HALO] = acc[it];  // left halo
        }
    }
    __syncthreads();
}

// one reconstruction iteration: appr (len S, sbuf w/ halo) + dseg (len S) -> len 2S.
// Outputs j=2m and j=(2m-1) mod 2S share window w = m-8+t (t in [0,16)):
//   out[2m]   += ho[31-2t]*a[w] + ho[2t]*d[w]
//   out[2m-1] += ho[30-2t]*a[w] - ho[2t+1]*d[w]
template<int S, bool STAGE_D>
__device__ inline void recon_step(float* sbuf, float* dbuf,
                                  const float* __restrict__ dglob,
                                  const float* __restrict__ ho, int tid)
{
    constexpr int N2 = 2 * S;
    constexpr int PT = (S + B_THREADS - 1) / B_THREADS;
    if (STAGE_D) {
        for (int t = tid; t < S + 16; t += B_THREADS)
            dbuf[t] = dglob[(t - 8) & (S - 1)];
        __syncthreads();
    }
    float acc_e[PT], acc_o[PT];
    #pragma unroll
    for (int it = 0; it < PT; ++it) {
        const int m = tid + it * B_THREADS;
        float oe = 0.f, oo = 0.f;
        if (m < S) {
            const float* pa = &sbuf[SB_HALO + m - 8];
            float dwin[16];
            if (STAGE_D) {
                const float* pd = &dbuf[m];
                #pragma unroll
                for (int t = 0; t < 16; ++t) dwin[t] = pd[t];
            } else if (m >= 8 && m < S - 7) {
                #pragma unroll
                for (int t = 0; t < 16; ++t) dwin[t] = dglob[m - 8 + t];
            } else {
                #pragma unroll
                for (int t = 0; t < 16; ++t) dwin[t] = dglob[(m - 8 + t) & (S - 1)];
            }
            #pragma unroll
            for (int t = 0; t < 16; ++t) {
                const float av = pa[t];
                const float dv = dwin[t];
                oe += ho[31 - 2 * t] * av + ho[2 * t] * dv;
                oo += ho[30 - 2 * t] * av - ho[2 * t + 1] * dv;
            }
        }
        acc_e[it] = oe; acc_o[it] = oo;
    }
    __syncthreads();
    #pragma unroll
    for (int it = 0; it < PT; ++it) {
        const int m = tid + it * B_THREADS;
        if (m < S) {
            const int je = 2 * m;
            const int jo = (2 * m - 1) & (N2 - 1);
            sbuf[SB_HALO + je] = acc_e[it];
            if (je < SB_HALO)       sbuf[SB_HALO + N2 + je] = acc_e[it];
            if (je >= N2 - SB_HALO) sbuf[je - N2 + SB_HALO] = acc_e[it];
            sbuf[SB_HALO + jo] = acc_o[it];
            if (jo < SB_HALO)       sbuf[SB_HALO + N2 + jo] = acc_o[it];
            if (jo >= N2 - SB_HALO) sbuf[jo - N2 + SB_HALO] = acc_o[it];
        }
    }
    __syncthreads();
}

__global__ __launch_bounds__(B_THREADS, 4) void wavelet_kernel(
    const float* __restrict__ ho, float* __restrict__ energy, float* __restrict__ apr)
{
    __shared__ float sbuf[SBUF_N];     // 131,200 B
    __shared__ float dbuf[DBUF_N];     //  16,448 B  (total 147,648 <= 160 KiB)
    const int tid = threadIdx.x;
    const int b = blockIdx.x;
    float* eb = energy + (size_t)b * L_FULL;
    float* ab = apr + (size_t)b * L_FULL;

    // load a1 (from kernel A) with circular halo
    for (int t = tid; t < SBUF_N; t += B_THREADS)
        sbuf[t] = ab[(t - SB_HALO) & (L_FULL / 2 - 1)];
    __syncthreads();

    // ---- decomposition, levels 2..8 (detail l at energy offset 65536 - (65536>>(l-1))) ----
    decomp_step<32768>(sbuf, ho, eb + 32768, tid);
    decomp_step<16384>(sbuf, ho, eb + 49152, tid);
    decomp_step< 8192>(sbuf, ho, eb + 57344, tid);
    decomp_step< 4096>(sbuf, ho, eb + 61440, tid);
    decomp_step< 2048>(sbuf, ho, eb + 63488, tid);
    decomp_step< 1024>(sbuf, ho, eb + 64512, tid);
    decomp_step<  512>(sbuf, ho, eb + 65024, tid);

    // a8 -> energy tail [65280, 65536)
    if (tid < 256) eb[65280 + tid] = sbuf[SB_HALO + tid];
    __syncthreads();

    // ---- reconstruction ----
    recon_step<  256, true >(sbuf, dbuf, eb + 65024, ho, tid);  // d8 -> 512
    recon_step<  512, true >(sbuf, dbuf, eb + 64512, ho, tid);  // d7 -> 1024
    recon_step< 1024, true >(sbuf, dbuf, eb + 63488, ho, tid);  // d6 -> 2048
    recon_step< 2048, true >(sbuf, dbuf, eb + 61440, ho, tid);  // d5 -> 4096
    recon_step< 4096, true >(sbuf, dbuf, eb + 57344, ho, tid);  // d4 -> 8192
    recon_step< 8192, false>(sbuf, dbuf, eb + 49152, ho, tid);  // d3 -> 16384
    recon_step<16384, false>(sbuf, dbuf, eb + 32768, ho, tid);  // d2 -> 32768

    // final iteration: 32768 -> 65536, d1 = eb[0..32768), write appr directly
    {
        constexpr int S = L_FULL / 2;
        const float* d1 = eb;
        #pragma unroll 4
        for (int it = 0; it < S / B_THREADS; ++it) {   // 32 iterations
            const int m = tid + it * B_THREADS;
            const float* pa = &sbuf[SB_HALO + m - 8];
            float dwin[16];
            if (m >= 8 && m < S - 7) {
                #pragma unroll
                for (int t = 0; t < 16; ++t) dwin[t] = d1[m - 8 + t];
            } else {
                #pragma unroll
                for (int t = 0; t < 16; ++t) dwin[t] = d1[(m - 8 + t) & (S - 1)];
            }
            float oe = 0.f, oo = 0.f;
            #pragma unroll
            for (int t = 0; t < 16; ++t) {
                const float av = pa[t];
                const float dv = dwin[t];
                oe += ho[31 - 2 * t] * av + ho[2 * t] * dv;
                oo += ho[30 - 2 * t] * av - ho[2 * t + 1] * dv;
            }
            ab[2 * m] = oe;
            ab[(2 * m - 1) & (L_FULL - 1)] = oo;
        }
    }
}

extern "C" void kernel_launch(void* const* d_in, const int* in_sizes, int n_in,
                              void* d_out, int out_size, void* d_ws, size_t ws_size,
                              hipStream_t stream)
{
    const float* x  = (const float*)d_in[0];
    const float* ho = (const float*)d_in[1];
    float* energy = (float*)d_out;                       // output 0: 256*65536
    float* apr    = energy + (size_t)BATCH * L_FULL;     // output 1: 256*65536

    level1_kernel<<<BATCH * A_BLOCKS_PER_B, A_THREADS, 0, stream>>>(x, ho, energy, apr);
    wavelet_kernel<<<BATCH, B_THREADS, 0, stream>>>(ho, energy, apr);
}

// Round 9
// 300.862 us; speedup vs baseline: 2.7150x; 2.6647x over previous
//
#include <hip/hip_runtime.h>

#define L_FULL 65536
#define BATCH 256
#define F_TAPS 32

// ================= Kernel A: level-1 decomposition (validated r4/r7) =========
// a1[j] = sum_k ho[k]*x[(2j+k-15) mod L]; d1 with g[k] = (-1)^(k+1) ho[31-k].
constexpr int A_THREADS = 256;
constexpr int A_OUT = 2048;
constexpr int A_BLOCKS_PER_B = (L_FULL / 2) / A_OUT;  // 16

__global__ __launch_bounds__(A_THREADS) void level1_kernel(
    const float* __restrict__ x, const float* __restrict__ ho,
    float* __restrict__ energy, float* __restrict__ apr)
{
    __shared__ float xs[2 * A_OUT + 32];
    const int tid = threadIdx.x;
    const int b = blockIdx.x / A_BLOCKS_PER_B;
    const int chunk = blockIdx.x % A_BLOCKS_PER_B;
    const int j0 = chunk * A_OUT;

    const float* xb = x + (size_t)b * L_FULL;
    constexpr int NF4 = (2 * A_OUT + 32) / 4;
    for (int q = tid; q < NF4; q += A_THREADS) {
        const int fidx = (2 * j0 - 16 + 4 * q) & (L_FULL - 1);
        *reinterpret_cast<float4*>(&xs[4 * q]) =
            *reinterpret_cast<const float4*>(&xb[fidx]);
    }
    __syncthreads();

    float* eb = energy + (size_t)b * L_FULL;
    float* ab = apr + (size_t)b * L_FULL;
    #pragma unroll
    for (int it = 0; it < A_OUT / A_THREADS; ++it) {
        const int j = tid + it * A_THREADS;
        const float* p = &xs[2 * j + 1];
        float aa = 0.f, dd = 0.f;
        #pragma unroll
        for (int k = 0; k < F_TAPS; ++k) {
            const float v = p[k];
            aa += ho[k] * v;
            dd += (k & 1) ? ho[31 - k] * v : -ho[31 - k] * v;
        }
        eb[j0 + j] = dd;
        ab[j0 + j] = aa;
    }
}

// ================= Grid-parallel decomposition (one level) ===================
// in/aout/dout are SLOT pointers (batch row = ptr + b*L_FULL). M outputs.
constexpr int DG_THREADS = 256;
constexpr int DG_C = 1024;   // outputs per block

__global__ __launch_bounds__(DG_THREADS) void decomp_g(
    const float* __restrict__ in, const float* __restrict__ ho,
    float* __restrict__ aout, float* __restrict__ dout,
    int M, int chunks)
{
    __shared__ float xs[2 * DG_C + 32];
    const int tid = threadIdx.x;
    const int b = blockIdx.x / chunks;
    const int c = blockIdx.x % chunks;
    const int j0 = c * DG_C;
    const int mask = 2 * M - 1;

    const float* rin = in + (size_t)b * L_FULL;
    for (int q = tid; q < (2 * DG_C + 32) / 4; q += DG_THREADS) {
        const int fidx = (2 * j0 - 16 + 4 * q) & mask;   // mult of 4, no quad-straddle
        *reinterpret_cast<float4*>(&xs[4 * q]) =
            *reinterpret_cast<const float4*>(&rin[fidx]);
    }
    __syncthreads();

    float* ra = aout + (size_t)b * L_FULL;
    float* rd = dout + (size_t)b * L_FULL;
    #pragma unroll
    for (int it = 0; it < DG_C / DG_THREADS; ++it) {
        const int j = tid + it * DG_THREADS;
        const float* p = &xs[2 * j + 1];                 // = a[2(j0+j)-15 ..]
        float aa = 0.f, dd = 0.f;
        #pragma unroll
        for (int k = 0; k < F_TAPS; ++k) {
            const float v = p[k];
            aa += ho[k] * v;
            dd += (k & 1) ? ho[31 - k] * v : -ho[31 - k] * v;
        }
        ra[j0 + j] = aa;
        rd[j0 + j] = dd;
    }
}

// ================= Grid-parallel reconstruction (one level) ==================
// out[2m] = sum_t ho[31-2t]*A[w] + ho[2t]*D[w]; out[2m-1] = ho[30-2t]*A[w] - ho[2t+1]*D[w]
// w = (m-8+t) mod S.  Strided slot pointers; per-pointer batch stride.
constexpr int RG_THREADS = 256;
constexpr int RG_C = 512;    // m's per block

__global__ __launch_bounds__(RG_THREADS) void recon_g(
    const float* __restrict__ inA, long strideA,
    const float* __restrict__ inD,
    float* __restrict__ out, long strideO,
    const float* __restrict__ ho, int S, int chunks)
{
    __shared__ float as_[RG_C + 16], ds_[RG_C + 16];
    const int tid = threadIdx.x;
    const int b = blockIdx.x / chunks;
    const int c = blockIdx.x % chunks;
    const int m0 = c * RG_C;
    const int mask = S - 1;

    const float* rA = inA + (size_t)b * strideA;
    const float* rD = inD + (size_t)b * L_FULL;
    for (int q = tid; q < (RG_C + 16) / 4; q += RG_THREADS) {
        const int idx = (m0 - 8 + 4 * q) & mask;         // mult of 4
        *reinterpret_cast<float4*>(&as_[4 * q]) = *reinterpret_cast<const float4*>(&rA[idx]);
        *reinterpret_cast<float4*>(&ds_[4 * q]) = *reinterpret_cast<const float4*>(&rD[idx]);
    }
    __syncthreads();

    float* rO = out + (size_t)b * strideO;
    const int n2mask = 2 * S - 1;
    #pragma unroll
    for (int it = 0; it < RG_C / RG_THREADS; ++it) {
        const int ml = tid + it * RG_THREADS;
        const int m = m0 + ml;
        float oe = 0.f, oo = 0.f;
        #pragma unroll
        for (int t = 0; t < 16; ++t) {
            const float av = as_[ml + t];
            const float dv = ds_[ml + t];
            oe += ho[31 - 2 * t] * av + ho[2 * t] * dv;
            oo += ho[30 - 2 * t] * av - ho[2 * t + 1] * dv;
        }
        rO[2 * m] = oe;
        rO[(2 * m - 1) & n2mask] = oo;
    }
}

// ================= MID kernel: levels 4..8 both directions, LDS ping-pong ====
constexpr int MID_THREADS = 512;
constexpr int HB = 16;

__device__ inline void mid_dstep(const float* __restrict__ src, float* __restrict__ dst,
                                 int N, float* __restrict__ dglob,
                                 const float* __restrict__ ho, int tid)
{
    const int M = N / 2;
    for (int j = tid; j < M; j += MID_THREADS) {
        const float* p = &src[HB + 2 * j - 15];
        float aa = 0.f, dd = 0.f;
        #pragma unroll
        for (int k = 0; k < F_TAPS; ++k) {
            const float v = p[k];
            aa += ho[k] * v;
            dd += (k & 1) ? ho[31 - k] * v : -ho[31 - k] * v;
        }
        dglob[j] = dd;
        dst[HB + j] = aa;
        if (j < 16)      dst[HB + M + j] = aa;
        if (j >= M - 16) dst[HB + j - M] = aa;
    }
    __syncthreads();
}

__device__ inline void mid_rstep(const float* __restrict__ src, float* __restrict__ dst,
                                 int S, const float* __restrict__ drow,
                                 const float* __restrict__ ho, int tid, float* __restrict__ dl)
{
    for (int t = tid; t < S + 16; t += MID_THREADS)
        dl[t] = drow[(t - 8) & (S - 1)];
    __syncthreads();
    const int n2 = 2 * S;
    for (int m = tid; m < S; m += MID_THREADS) {
        const float* pa = &src[HB + m - 8];
        const float* pd = &dl[m];
        float oe = 0.f, oo = 0.f;
        #pragma unroll
        for (int t = 0; t < 16; ++t) {
            const float av = pa[t];
            const float dv = pd[t];
            oe += ho[31 - 2 * t] * av + ho[2 * t] * dv;
            oo += ho[30 - 2 * t] * av - ho[2 * t + 1] * dv;
        }
        const int je = 2 * m;
        const int jo = (2 * m - 1) & (n2 - 1);
        dst[HB + je] = oe;
        if (je < 16)      dst[HB + n2 + je] = oe;
        if (je >= n2 - 16) dst[HB + je - n2] = oe;
        dst[HB + jo] = oo;
        if (jo < 16)      dst[HB + n2 + jo] = oo;
        if (jo >= n2 - 16) dst[HB + jo - n2] = oo;
    }
    __syncthreads();
}

__global__ __launch_bounds__(MID_THREADS) void mid_kernel(
    const float* __restrict__ ho, float* __restrict__ energy,
    const float* __restrict__ a3in, float* __restrict__ a3out)
{
    __shared__ float bufA[8192 + 32], bufB[8192 + 32], dl[4096 + 16];  // ~82 KB
    const int tid = threadIdx.x;
    const int b = blockIdx.x;
    const float* rin = a3in + (size_t)b * L_FULL;
    float* re = energy + (size_t)b * L_FULL;

    // stage a3 (8192) with +-16 circular halo
    for (int q = tid; q < (8192 + 32) / 4; q += MID_THREADS) {
        const int idx = (4 * q - 16) & 8191;
        *reinterpret_cast<float4*>(&bufA[4 * q]) =
            *reinterpret_cast<const float4*>(&rin[idx]);
    }
    __syncthreads();

    // decomposition levels 4..8 (detail offsets: 57344,61440,63488,64512,65024)
    mid_dstep(bufA, bufB, 8192, re + 57344, ho, tid);   // a3->a4(B), d4
    mid_dstep(bufB, bufA, 4096, re + 61440, ho, tid);   // ->a5(A), d5
    mid_dstep(bufA, bufB, 2048, re + 63488, ho, tid);   // ->a6(B), d6
    mid_dstep(bufB, bufA, 1024, re + 64512, ho, tid);   // ->a7(A), d7
    mid_dstep(bufA, bufB,  512, re + 65024, ho, tid);   // ->a8(B), d8

    // a8 -> energy tail
    for (int j = tid; j < 256; j += MID_THREADS) re[65280 + j] = bufB[HB + j];

    // reconstruction up to a3' (8192)
    mid_rstep(bufB, bufA,  256, re + 65024, ho, tid, dl);  // +d8 -> 512 (A)
    mid_rstep(bufA, bufB,  512, re + 64512, ho, tid, dl);  // +d7 -> 1024 (B)
    mid_rstep(bufB, bufA, 1024, re + 63488, ho, tid, dl);  // +d6 -> 2048 (A)
    mid_rstep(bufA, bufB, 2048, re + 61440, ho, tid, dl);  // +d5 -> 4096 (B)
    mid_rstep(bufB, bufA, 4096, re + 57344, ho, tid, dl);  // +d4 -> 8192 (A)

    float* rout = a3out + (size_t)b * L_FULL;
    for (int j = tid; j < 8192; j += MID_THREADS) rout[j] = bufA[HB + j];
}

// ================= Fallback: validated round-4 fused kernel (ws too small) ===
constexpr int B_THREADS = 1024;
constexpr int SB_HALO = 16;
constexpr int SBUF_N = L_FULL / 2 + 2 * SB_HALO;
constexpr int DBUF_N = 4096 + 16;

template<int N>
__device__ inline void decomp_step(float* sbuf, const float* __restrict__ ho,
                                   float* __restrict__ dglob, int tid)
{
    constexpr int M = N / 2;
    constexpr int PT = (M + B_THREADS - 1) / B_THREADS;
    float acc[PT];
    #pragma unroll
    for (int it = 0; it < PT; ++it) {
        const int j = tid + it * B_THREADS;
        float aa = 0.f;
        if (j < M) {
            const float* p = &sbuf[2 * j + 1];
            float dd = 0.f;
            #pragma unroll
            for (int k = 0; k < F_TAPS; ++k) {
                const float v = p[k];
                aa += ho[k] * v;
                dd += (k & 1) ? ho[31 - k] * v : -ho[31 - k] * v;
            }
            dglob[j] = dd;
        }
        acc[it] = aa;
    }
    __syncthreads();
    #pragma unroll
    for (int it = 0; it < PT; ++it) {
        const int j = tid + it * B_THREADS;
        if (j < M) {
            sbuf[SB_HALO + j] = acc[it];
            if (j < SB_HALO)      sbuf[SB_HALO + M + j] = acc[it];
            if (j >= M - SB_HALO) sbuf[j - M + SB_HALO] = acc[it];
        }
    }
    __syncthreads();
}

template<int S, bool STAGE_D>
__device__ inline void recon_step(float* sbuf, float* dbuf,
                                  const float* __restrict__ dglob,
                                  const float* __restrict__ ho, int tid)
{
    constexpr int N2 = 2 * S;
    constexpr int PT = (S + B_THREADS - 1) / B_THREADS;
    if (STAGE_D) {
        for (int t = tid; t < S + 16; t += B_THREADS)
            dbuf[t] = dglob[(t - 8) & (S - 1)];
        __syncthreads();
    }
    float acc_e[PT], acc_o[PT];
    #pragma unroll
    for (int it = 0; it < PT; ++it) {
        const int m = tid + it * B_THREADS;
        float oe = 0.f, oo = 0.f;
        if (m < S) {
            const float* pa = &sbuf[SB_HALO + m - 8];
            float dwin[16];
            if (STAGE_D) {
                const float* pd = &dbuf[m];
                #pragma unroll
                for (int t = 0; t < 16; ++t) dwin[t] = pd[t];
            } else if (m >= 8 && m < S - 7) {
                #pragma unroll
                for (int t = 0; t < 16; ++t) dwin[t] = dglob[m - 8 + t];
            } else {
                #pragma unroll
                for (int t = 0; t < 16; ++t) dwin[t] = dglob[(m - 8 + t) & (S - 1)];
            }
            #pragma unroll
            for (int t = 0; t < 16; ++t) {
                const float av = pa[t];
                const float dv = dwin[t];
                oe += ho[31 - 2 * t] * av + ho[2 * t] * dv;
                oo += ho[30 - 2 * t] * av - ho[2 * t + 1] * dv;
            }
        }
        acc_e[it] = oe; acc_o[it] = oo;
    }
    __syncthreads();
    #pragma unroll
    for (int it = 0; it < PT; ++it) {
        const int m = tid + it * B_THREADS;
        if (m < S) {
            const int je = 2 * m;
            const int jo = (2 * m - 1) & (N2 - 1);
            sbuf[SB_HALO + je] = acc_e[it];
            if (je < SB_HALO)       sbuf[SB_HALO + N2 + je] = acc_e[it];
            if (je >= N2 - SB_HALO) sbuf[je - N2 + SB_HALO] = acc_e[it];
            sbuf[SB_HALO + jo] = acc_o[it];
            if (jo < SB_HALO)       sbuf[SB_HALO + N2 + jo] = acc_o[it];
            if (jo >= N2 - SB_HALO) sbuf[jo - N2 + SB_HALO] = acc_o[it];
        }
    }
    __syncthreads();
}

__global__ __launch_bounds__(B_THREADS) void wavelet_kernel(
    const float* __restrict__ ho, float* __restrict__ energy, float* __restrict__ apr)
{
    __shared__ float sbuf[SBUF_N];
    __shared__ float dbuf[DBUF_N];
    const int tid = threadIdx.x;
    const int b = blockIdx.x;
    float* eb = energy + (size_t)b * L_FULL;
    float* ab = apr + (size_t)b * L_FULL;

    for (int t = tid; t < SBUF_N; t += B_THREADS)
        sbuf[t] = ab[(t - SB_HALO) & (L_FULL / 2 - 1)];
    __syncthreads();

    decomp_step<32768>(sbuf, ho, eb + 32768, tid);
    decomp_step<16384>(sbuf, ho, eb + 49152, tid);
    decomp_step< 8192>(sbuf, ho, eb + 57344, tid);
    decomp_step< 4096>(sbuf, ho, eb + 61440, tid);
    decomp_step< 2048>(sbuf, ho, eb + 63488, tid);
    decomp_step< 1024>(sbuf, ho, eb + 64512, tid);
    decomp_step<  512>(sbuf, ho, eb + 65024, tid);

    if (tid < 256) eb[65280 + tid] = sbuf[SB_HALO + tid];
    __syncthreads();

    recon_step<  256, true >(sbuf, dbuf, eb + 65024, ho, tid);
    recon_step<  512, true >(sbuf, dbuf, eb + 64512, ho, tid);
    recon_step< 1024, true >(sbuf, dbuf, eb + 63488, ho, tid);
    recon_step< 2048, true >(sbuf, dbuf, eb + 61440, ho, tid);
    recon_step< 4096, true >(sbuf, dbuf, eb + 57344, ho, tid);
    recon_step< 8192, false>(sbuf, dbuf, eb + 49152, ho, tid);
    recon_step<16384, false>(sbuf, dbuf, eb + 32768, ho, tid);

    {
        constexpr int S = L_FULL / 2;
        const float* d1 = eb;
        #pragma unroll 4
        for (int it = 0; it < S / B_THREADS; ++it) {
            const int m = tid + it * B_THREADS;
            const float* pa = &sbuf[SB_HALO + m - 8];
            float dwin[16];
            if (m >= 8 && m < S - 7) {
                #pragma unroll
                for (int t = 0; t < 16; ++t) dwin[t] = d1[m - 8 + t];
            } else {
                #pragma unroll
                for (int t = 0; t < 16; ++t) dwin[t] = d1[(m - 8 + t) & (S - 1)];
            }
            float oe = 0.f, oo = 0.f;
            #pragma unroll
            for (int t = 0; t < 16; ++t) {
                const float av = pa[t];
                const float dv = dwin[t];
                oe += ho[31 - 2 * t] * av + ho[2 * t] * dv;
                oo += ho[30 - 2 * t] * av - ho[2 * t + 1] * dv;
            }
            ab[2 * m] = oe;
            ab[(2 * m - 1) & (L_FULL - 1)] = oo;
        }
    }
}

// ================= launch =================
extern "C" void kernel_launch(void* const* d_in, const int* in_sizes, int n_in,
                              void* d_out, int out_size, void* d_ws, size_t ws_size,
                              hipStream_t stream)
{
    const float* x  = (const float*)d_in[0];
    const float* ho = (const float*)d_in[1];
    float* energy = (float*)d_out;                    // 256*65536
    float* apr    = energy + (size_t)BATCH * L_FULL;  // 256*65536
    float* W      = (float*)d_ws;                     // needs 256*32768 floats

    // K1: x -> a1 (apr slot0), d1 (energy[0:32768))
    level1_kernel<<<BATCH * A_BLOCKS_PER_B, A_THREADS, 0, stream>>>(x, ho, energy, apr);

    const size_t wneed = (size_t)BATCH * (L_FULL / 2) * sizeof(float);
    if (ws_size >= wneed) {
        // D2: a1(slot0) -> a2(slot1) + d2@32768
        decomp_g<<<BATCH * 16, DG_THREADS, 0, stream>>>(apr, ho, apr + 32768, energy + 32768, 16384, 16);
        // D3: a2(slot1) -> a3(slot0) + d3@49152
        decomp_g<<<BATCH * 8, DG_THREADS, 0, stream>>>(apr + 32768, ho, apr, energy + 49152, 8192, 8);
        // MID: a3(slot0) -> d4..d8,a8 -> recon -> a3'(slot1)
        mid_kernel<<<BATCH, MID_THREADS, 0, stream>>>(ho, energy, apr, apr + 32768);
        // R5: a3'(slot1) + d3 -> a2'(slot0), S=8192
        recon_g<<<BATCH * 16, RG_THREADS, 0, stream>>>(apr + 32768, (long)L_FULL, energy + 49152,
                                                       apr, (long)L_FULL, ho, 8192, 16);
        // R6: a2'(slot0) + d2 -> a1'(W), S=16384
        recon_g<<<BATCH * 32, RG_THREADS, 0, stream>>>(apr, (long)L_FULL, energy + 32768,
                                                       W, 32768L, ho, 16384, 32);
        // R7: a1'(W) + d1 -> apr full, S=32768
        recon_g<<<BATCH * 64, RG_THREADS, 0, stream>>>(W, 32768L, energy,
                                                       apr, (long)L_FULL, ho, 32768, 64);
    } else {
        wavelet_kernel<<<BATCH, B_THREADS, 0, stream>>>(ho, energy, apr);
    }
}